// Round 1
// baseline (624.613 us; speedup 1.0000x reference)
//
#include <hip/hip_runtime.h>
#include <hip/hip_bf16.h>

// Problem: int8 quantized conv2d 3x3 s1 p1. B=32 Cin=128 H=W=56 Cout=256.
// x: (32,128,56,56) f32, w: (256,128,3,3) f32, bias: (256,) f32
// out: (32,256,56,56) f32

#define B_    32
#define CIN   128
#define H_    56
#define W_    56
#define COUT  256
#define HP    58   // padded spatial
#define WP    58

// int8 dot4: d = a.b (4 signed bytes each) + c
__device__ __forceinline__ int dot4(int a, int b, int c) {
#if __has_builtin(__builtin_amdgcn_sdot4)
    return __builtin_amdgcn_sdot4(a, b, c, false);
#else
    int s = c;
    s += (int)(signed char)(a)       * (int)(signed char)(b);
    s += (int)(signed char)(a >> 8)  * (int)(signed char)(b >> 8);
    s += (int)(signed char)(a >> 16) * (int)(signed char)(b >> 16);
    s += (int)(signed char)(a >> 24) * (int)(signed char)(b >> 24);
    return s;
#endif
}

// ---------------- amax reduction ----------------
__global__ void amax_kernel(const float4* __restrict__ p, long n4, unsigned* __restrict__ slot) {
    float m = 0.f;
    long stride = (long)gridDim.x * blockDim.x;
    for (long i = (long)blockIdx.x * blockDim.x + threadIdx.x; i < n4; i += stride) {
        float4 v = p[i];
        m = fmaxf(m, fmaxf(fmaxf(fabsf(v.x), fabsf(v.y)), fmaxf(fabsf(v.z), fabsf(v.w))));
    }
    __shared__ float red[256];
    red[threadIdx.x] = m;
    __syncthreads();
    for (int s = 128; s > 0; s >>= 1) {
        if (threadIdx.x < s) red[threadIdx.x] = fmaxf(red[threadIdx.x], red[threadIdx.x + s]);
        __syncthreads();
    }
    if (threadIdx.x == 0) atomicMax(slot, __float_as_uint(red[0]));  // all >=0: uint order == float order
}

// ---------------- quantize x: NCHW f32 -> padded NHWC int8 ----------------
// xq[b][h+1][w+1][c] layout (HP x WP spatial, CIN innermost). Pad pre-zeroed by memset.
__global__ void quant_x_kernel(const float4* __restrict__ x4, const unsigned* __restrict__ scales,
                               signed char* __restrict__ xq) {
    const long n4 = (long)B_ * CIN * H_ * W_ / 4;   // 3,211,264
    long t = (long)blockIdx.x * blockDim.x + threadIdx.x;
    if (t >= n4) return;
    float ax = __uint_as_float(scales[0]);
    float sx = 127.0f / ax;
    int e  = (int)(t * 4);          // NCHW linear element index (fits int)
    int w  = e % W_;                // 56 divisible by 4: the 4 elems stay in-row
    int hw = e / W_;
    int h  = hw % H_;
    int bc = hw / H_;
    int c  = bc % CIN;
    int b  = bc / CIN;
    float4 v = x4[t];
    float q0 = fminf(127.f, fmaxf(-127.f, rintf(v.x * sx)));
    float q1 = fminf(127.f, fmaxf(-127.f, rintf(v.y * sx)));
    float q2 = fminf(127.f, fmaxf(-127.f, rintf(v.z * sx)));
    float q3 = fminf(127.f, fmaxf(-127.f, rintf(v.w * sx)));
    int base = (((b * HP) + h + 1) * WP + (w + 1)) * CIN + c;
    xq[base]           = (signed char)(int)q0;
    xq[base + CIN]     = (signed char)(int)q1;
    xq[base + 2 * CIN] = (signed char)(int)q2;
    xq[base + 3 * CIN] = (signed char)(int)q3;
}

// ---------------- quantize w: OIHW f32 -> (Cout,3,3,Cin) int8 ----------------
__global__ void quant_w_kernel(const float* __restrict__ wt, const unsigned* __restrict__ scales,
                               signed char* __restrict__ wq) {
    const int n = COUT * CIN * 9;   // 294,912
    int idx = blockIdx.x * blockDim.x + threadIdx.x;
    if (idx >= n) return;
    float aw = __uint_as_float(scales[1]);
    float sw = 127.0f / aw;
    int kw = idx % 3;
    int t1 = idx / 3;
    int kh = t1 % 3;
    int t2 = t1 / 3;
    int ci = t2 % CIN;
    int co = t2 / CIN;
    float q = fminf(127.f, fmaxf(-127.f, rintf(wt[idx] * sw)));
    wq[((co * 9) + kh * 3 + kw) * CIN + ci] = (signed char)(int)q;
}

// ---------------- conv: int8 x int8 -> int32, fused dequant + bias ----------------
#define COPT 8   // cout per thread
__global__ __launch_bounds__(256) void conv_kernel(
        const signed char* __restrict__ xq, const signed char* __restrict__ wq,
        const float* __restrict__ bias, const unsigned* __restrict__ scales,
        float* __restrict__ out) {
    const int tid = threadIdx.x;
    const int p = blockIdx.x * 256 + tid;      // pixel in 56x56 plane
    if (p >= H_ * W_) return;
    const int h = p / W_;
    const int w = p % W_;
    const int b = blockIdx.z;
    const int co0 = blockIdx.y * COPT;

    int acc[COPT];
#pragma unroll
    for (int i = 0; i < COPT; ++i) acc[i] = 0;

    const int4* __restrict__ xv = (const int4*)xq;   // 16 int8 per int4
    const int4* __restrict__ wv = (const int4*)wq;

    for (int kh = 0; kh < 3; ++kh) {
        for (int kw = 0; kw < 3; ++kw) {
            const int xbase = (((b * HP) + h + kh) * WP + (w + kw)) * (CIN / 16); // int4 units
            const int tap = kh * 3 + kw;
#pragma unroll
            for (int c16 = 0; c16 < CIN / 16; ++c16) {
                const int4 xb = xv[xbase + c16];
#pragma unroll
                for (int co = 0; co < COPT; ++co) {
                    const int4 wb = wv[((co0 + co) * 9 + tap) * (CIN / 16) + c16];
                    acc[co] = dot4(xb.x, wb.x, acc[co]);
                    acc[co] = dot4(xb.y, wb.y, acc[co]);
                    acc[co] = dot4(xb.z, wb.z, acc[co]);
                    acc[co] = dot4(xb.w, wb.w, acc[co]);
                }
            }
        }
    }

    const float ax = __uint_as_float(scales[0]);
    const float aw = __uint_as_float(scales[1]);
    const float sx = 127.0f / ax;
    const float sw = 127.0f / aw;
    const float inv = 1.0f / (sx * sw);
#pragma unroll
    for (int co = 0; co < COPT; ++co) {
        out[((long)(b * COUT + co0 + co)) * (H_ * W_) + p] =
            (float)acc[co] * inv + bias[co0 + co];
    }
}

extern "C" void kernel_launch(void* const* d_in, const int* in_sizes, int n_in,
                              void* d_out, int out_size, void* d_ws, size_t ws_size,
                              hipStream_t stream) {
    const float* x  = (const float*)d_in[0];
    const float* wt = (const float*)d_in[1];
    const float* bs = (const float*)d_in[2];
    float* out = (float*)d_out;

    // workspace layout
    unsigned* scales = (unsigned*)d_ws;                          // [0]=amax_x bits, [1]=amax_w bits
    const size_t XQ_OFF   = 256;
    const size_t XQ_BYTES = (size_t)B_ * HP * WP * CIN;          // 13,778,944
    signed char* xq = (signed char*)d_ws + XQ_OFF;
    signed char* wq = xq + XQ_BYTES;

    // zero scales + padded xq (padding must be 0)
    hipMemsetAsync(d_ws, 0, XQ_OFF + XQ_BYTES, stream);

    // amax reductions
    const long n4x = (long)B_ * CIN * H_ * W_ / 4;   // 3,211,264
    const long n4w = (long)COUT * CIN * 9 / 4;       // 73,728
    amax_kernel<<<2048, 256, 0, stream>>>((const float4*)x, n4x, scales + 0);
    amax_kernel<<<288, 256, 0, stream>>>((const float4*)wt, n4w, scales + 1);

    // quantize
    quant_x_kernel<<<(int)((n4x + 255) / 256), 256, 0, stream>>>((const float4*)x, scales, xq);
    quant_w_kernel<<<(COUT * CIN * 9 + 255) / 256, 256, 0, stream>>>(wt, scales, wq);

    // conv + dequant + bias
    dim3 grid((H_ * W_ + 255) / 256, COUT / COPT, B_);
    conv_kernel<<<grid, 256, 0, stream>>>(xq, wq, bs, scales, out);
}

// Round 2
// 268.009 us; speedup vs baseline: 2.3306x; 2.3306x over previous
//
#include <hip/hip_runtime.h>
#include <hip/hip_bf16.h>

// int8 quantized conv2d 3x3 s1 p1. B=32 Cin=128 H=W=56 Cout=256.
// Implicit GEMM: D[co][px] = sum_k W[co][k] * X[k][px], K = 9*128 = 1152.
// MFMA i32_16x16x64_i8; A = weights packed [chunk][cout][64B], B = padded NHWC activations.

#define B_    32
#define CIN   128
#define H_    56
#define W_    56
#define COUT  256
#define HP    58
#define WP    58
#define HWP   (H_*W_)        // 3136
#define NPIX  (B_*HWP)       // 100352
#define NCHUNK 18            // K=1152 / 64

typedef int int4v __attribute__((ext_vector_type(4)));

// ---------------- fused amax over x and w ----------------
__global__ __launch_bounds__(256) void amax_kernel(const float4* __restrict__ x, long n4x,
                                                   const float4* __restrict__ wt, long n4w,
                                                   unsigned* __restrict__ scales) {
    const float4* p; long n4; unsigned* slot; long start, stride;
    if (blockIdx.x < 2048) {
        p = x; n4 = n4x; slot = scales;
        start = (long)blockIdx.x * 256 + threadIdx.x; stride = 2048L * 256;
    } else {
        p = wt; n4 = n4w; slot = scales + 1;
        start = (long)(blockIdx.x - 2048) * 256 + threadIdx.x; stride = 128L * 256;
    }
    float m = 0.f;
    for (long i = start; i < n4; i += stride) {
        float4 v = p[i];
        m = fmaxf(m, fmaxf(fmaxf(fabsf(v.x), fabsf(v.y)), fmaxf(fabsf(v.z), fabsf(v.w))));
    }
    __shared__ float red[256];
    red[threadIdx.x] = m; __syncthreads();
    for (int s = 128; s > 0; s >>= 1) {
        if (threadIdx.x < s) red[threadIdx.x] = fmaxf(red[threadIdx.x], red[threadIdx.x + s]);
        __syncthreads();
    }
    if (threadIdx.x == 0) atomicMax(slot, __float_as_uint(red[0]));  // all >=0
}

// ---------------- quantize x: NCHW f32 -> padded NHWC int8 (LDS transpose) ----------------
// block = one (b,h) row: 128 c x 56 w. LDS int[56][33] (+1 pad -> conflict-free).
__global__ __launch_bounds__(256) void quant_x_kernel(const float* __restrict__ x,
        const unsigned* __restrict__ scales, signed char* __restrict__ xq) {
    const int bh = blockIdx.x;
    const int b = bh / H_, h = bh % H_;
    const float sx = 127.0f / __uint_as_float(scales[0]);
    __shared__ int ldsq[W_ * 33];
    const int tid = threadIdx.x;
    const int w = tid & 63;
    const int chi = tid >> 6;   // 0..3
    if (w < W_) {
        const float* xb = x + (long)b * CIN * HWP + h * W_ + w;
#pragma unroll
        for (int it = 0; it < 8; ++it) {
            const int c4 = it * 4 + chi;     // 0..31
            int pk = 0;
#pragma unroll
            for (int u = 0; u < 4; ++u) {
                float v = xb[(long)(c4 * 4 + u) * HWP];
                float q = fminf(127.f, fmaxf(-127.f, rintf(v * sx)));
                pk |= ((int)q & 0xff) << (u * 8);
            }
            ldsq[w * 33 + c4] = pk;
        }
    }
    __syncthreads();
    // 448 int4 stores: fully coalesced NHWC rows
    int4* dst = (int4*)(xq + (((long)b * HP + h + 1) * WP + 1) * CIN);
    for (int idx = tid; idx < W_ * 8; idx += 256) {
        const int ww = idx >> 3, c16 = idx & 7;
        int4 v;
        v.x = ldsq[ww * 33 + c16 * 4 + 0];
        v.y = ldsq[ww * 33 + c16 * 4 + 1];
        v.z = ldsq[ww * 33 + c16 * 4 + 2];
        v.w = ldsq[ww * 33 + c16 * 4 + 3];
        dst[ww * 8 + c16] = v;
    }
}

// ---------------- quantize w: OIHW f32 -> packed [chunk][cout][64] int8 ----------------
__global__ __launch_bounds__(256) void quant_w_kernel(const float* __restrict__ wt,
        const unsigned* __restrict__ scales, signed char* __restrict__ wq) {
    const int id = blockIdx.x * 256 + threadIdx.x;   // 256*9*32 = 73728
    if (id >= COUT * 9 * 32) return;
    const float sw = 127.0f / __uint_as_float(scales[1]);
    const int co = id / 288;
    const int r  = id % 288;
    const int t  = r / 32;    // tap 0..8 (kh*3+kw)
    const int c4 = r % 32;    // ci/4
    int pk = 0;
#pragma unroll
    for (int u = 0; u < 4; ++u) {
        float v = wt[(co * CIN + c4 * 4 + u) * 9 + t];
        float q = fminf(127.f, fmaxf(-127.f, rintf(v * sw)));
        pk |= ((int)q & 0xff) << (u * 8);
    }
    const int k = t * CIN + c4 * 4;          // tap-major K index
    const int chunk = k >> 6;
    const int off = k & 63;
    *(int*)(wq + (long)chunk * (COUT * 64) + co * 64 + off) = pk;
}

// ---------------- conv: MFMA implicit GEMM ----------------
// block 256 thr = 4 waves; block tile 128 px x 128 co; wave tile 64 px x 64 co.
__global__ __launch_bounds__(256) void conv_kernel(const signed char* __restrict__ xq,
        const signed char* __restrict__ wq, const float* __restrict__ bias,
        const unsigned* __restrict__ scales, float* __restrict__ out) {
    const int tid = threadIdx.x;
    const int lane = tid & 63;
    const int wv = tid >> 6;          // wave 0..3
    const int ln = lane & 15;
    const int g  = lane >> 4;

    const int wco = wv >> 1, wpx = wv & 1;
    const int co_base = blockIdx.y * 128 + wco * 64;
    const int px_base = blockIdx.x * 128 + wpx * 64;

    // A (weights): lane-constant byte offsets into packed wq
    int wbase[4];
#pragma unroll
    for (int i = 0; i < 4; ++i)
        wbase[i] = (co_base + i * 16 + ln) * 64 + g * 16;

    // B (pixels): per-lane base offsets into padded NHWC xq
    int xbase[4], bj[4], hwj[4];
#pragma unroll
    for (int j = 0; j < 4; ++j) {
        const int px = px_base + j * 16 + ln;
        const int b = px / HWP, hw = px % HWP;
        const int h = hw / W_, w = hw % W_;
        bj[j] = b; hwj[j] = hw;
        xbase[j] = ((b * HP + h) * WP + w) * CIN + g * 16;
    }

    int4v acc[4][4] = {};
    int4v Af[2][4], Bf[2][4];

    // chunk c: tap = c>>1, channel half = (c&1)*64
#define LOAD_A(dst, c) \
    _Pragma("unroll") for (int i = 0; i < 4; ++i) \
        dst[i] = *(const int4v*)(wq + (c) * (COUT * 64) + wbase[i]);
#define LOAD_B(dst, c) { \
    const int tap = (c) >> 1; \
    const int toff = ((tap / 3) * WP + (tap % 3)) * CIN + ((c) & 1) * 64; \
    _Pragma("unroll") for (int j = 0; j < 4; ++j) \
        dst[j] = *(const int4v*)(xq + xbase[j] + toff); }

    LOAD_A(Af[0], 0); LOAD_B(Bf[0], 0);
#pragma unroll
    for (int c = 0; c < NCHUNK; ++c) {
        const int cur = c & 1, nxt = cur ^ 1;
        if (c + 1 < NCHUNK) { LOAD_A(Af[nxt], c + 1); LOAD_B(Bf[nxt], c + 1); }
#pragma unroll
        for (int i = 0; i < 4; ++i)
#pragma unroll
            for (int j = 0; j < 4; ++j)
                acc[i][j] = __builtin_amdgcn_mfma_i32_16x16x64_i8(Af[cur][i], Bf[cur][j], acc[i][j], 0, 0, 0);
    }

    const float ax = __uint_as_float(scales[0]);
    const float aw = __uint_as_float(scales[1]);
    const float inv = 1.0f / ((127.0f / ax) * (127.0f / aw));

    // D layout (16x16): col(=px) = lane&15, row(=co) = g*4 + r
#pragma unroll
    for (int i = 0; i < 4; ++i) {
#pragma unroll
        for (int r = 0; r < 4; ++r) {
            const int co = co_base + i * 16 + g * 4 + r;
            const float bs = bias[co];
#pragma unroll
            for (int j = 0; j < 4; ++j) {
                const long o = ((long)(bj[j] * COUT + co)) * HWP + hwj[j];
                out[o] = (float)acc[i][j][r] * inv + bs;
            }
        }
    }
#undef LOAD_A
#undef LOAD_B
}

extern "C" void kernel_launch(void* const* d_in, const int* in_sizes, int n_in,
                              void* d_out, int out_size, void* d_ws, size_t ws_size,
                              hipStream_t stream) {
    const float* x  = (const float*)d_in[0];
    const float* wt = (const float*)d_in[1];
    const float* bs = (const float*)d_in[2];
    float* out = (float*)d_out;

    unsigned* scales = (unsigned*)d_ws;                  // [0]=amax_x bits, [1]=amax_w bits
    const size_t XQ_OFF   = 256;
    const size_t XQ_BYTES = (size_t)B_ * HP * WP * CIN;  // 13,778,944
    signed char* xq = (signed char*)d_ws + XQ_OFF;
    signed char* wq = xq + XQ_BYTES;                     // 294,912 B packed

    // zero scales + padded xq (padding must be 0); wq fully overwritten
    hipMemsetAsync(d_ws, 0, XQ_OFF + XQ_BYTES, stream);

    const long n4x = (long)B_ * CIN * H_ * W_ / 4;   // 3,211,264
    const long n4w = (long)COUT * CIN * 9 / 4;       // 73,728
    amax_kernel<<<2176, 256, 0, stream>>>((const float4*)x, n4x, (const float4*)wt, n4w, scales);

    quant_x_kernel<<<B_ * H_, 256, 0, stream>>>(x, scales, xq);
    quant_w_kernel<<<(COUT * 9 * 32 + 255) / 256, 256, 0, stream>>>(wt, scales, wq);

    dim3 grid(NPIX / 128, COUT / 128);
    conv_kernel<<<grid, 256, 0, stream>>>(xq, wq, bs, scales, out);
}

// Round 4
// 219.912 us; speedup vs baseline: 2.8403x; 1.2187x over previous
//
#include <hip/hip_runtime.h>
#include <hip/hip_bf16.h>

// int8 quantized conv2d 3x3 s1 p1. B=32 Cin=128 H=W=56 Cout=256.
// Implicit GEMM, LDS-pipelined MFMA i32_16x16x64_i8.
// A = weights packed [chunk][cout][64B], B = padded NHWC int8 activations.

#define B_    32
#define CIN   128
#define H_    56
#define W_    56
#define COUT  256
#define HP    58
#define WP    58
#define HWP   (H_*W_)        // 3136
#define NPIX  (B_*HWP)       // 100352
#define NCHUNK 18            // K=1152 / 64
#define CHUNK_BYTES (COUT*64) // 16384

typedef int int4v __attribute__((ext_vector_type(4)));

__device__ __forceinline__ void gld_lds16(const void* g, void* l) {
    __builtin_amdgcn_global_load_lds(
        (const __attribute__((address_space(1))) unsigned int*)g,
        (__attribute__((address_space(3))) unsigned int*)l, 16, 0, 0);
}

// ---------------- pad/scale zero (replaces 14MB memset) ----------------
__global__ __launch_bounds__(256) void pad_zero_kernel(signed char* __restrict__ xq,
                                                       unsigned* __restrict__ scales) {
    const int b = blockIdx.x;
    if (b == 0 && threadIdx.x < 2) scales[threadIdx.x] = 0;
    int4* base = (int4*)(xq + (long)b * HP * WP * CIN);
    const int ROWI4 = WP * CIN / 16;   // 464
    int4 z; z.x = 0; z.y = 0; z.z = 0; z.w = 0;
    for (int i = threadIdx.x; i < ROWI4; i += 256) base[i] = z;                  // row 0
    int4* top = base + 57 * ROWI4;
    for (int i = threadIdx.x; i < ROWI4; i += 256) top[i] = z;                   // row 57
    for (int idx = threadIdx.x; idx < 56 * 16; idx += 256) {                     // cols 0 & 57
        const int h = idx >> 4, c = idx & 15;
        const int w = (c < 8) ? 0 : 57, p = c & 7;
        base[(h + 1) * ROWI4 + w * (CIN / 16) + p] = z;
    }
}

// ---------------- fused amax over x and w ----------------
__global__ __launch_bounds__(256) void amax_kernel(const float4* __restrict__ x, long n4x,
                                                   const float4* __restrict__ wt, long n4w,
                                                   unsigned* __restrict__ scales) {
    const float4* p; long n4; unsigned* slot; long start, stride;
    if (blockIdx.x < 2048) {
        p = x; n4 = n4x; slot = scales;
        start = (long)blockIdx.x * 256 + threadIdx.x; stride = 2048L * 256;
    } else {
        p = wt; n4 = n4w; slot = scales + 1;
        start = (long)(blockIdx.x - 2048) * 256 + threadIdx.x; stride = 128L * 256;
    }
    float m = 0.f;
    for (long i = start; i < n4; i += stride) {
        float4 v = p[i];
        m = fmaxf(m, fmaxf(fmaxf(fabsf(v.x), fabsf(v.y)), fmaxf(fabsf(v.z), fabsf(v.w))));
    }
    __shared__ float red[256];
    red[threadIdx.x] = m; __syncthreads();
    for (int s = 128; s > 0; s >>= 1) {
        if (threadIdx.x < s) red[threadIdx.x] = fmaxf(red[threadIdx.x], red[threadIdx.x + s]);
        __syncthreads();
    }
    if (threadIdx.x == 0) atomicMax(slot, __float_as_uint(red[0]));  // all >=0
}

// ---------------- quantize x: NCHW f32 -> padded NHWC int8 (LDS transpose) ----------------
__global__ __launch_bounds__(256) void quant_x_kernel(const float* __restrict__ x,
        const unsigned* __restrict__ scales, signed char* __restrict__ xq) {
    const int bh = blockIdx.x;
    const int b = bh / H_, h = bh % H_;
    const float sx = 127.0f / __uint_as_float(scales[0]);
    __shared__ int ldsq[W_ * 33];
    const int tid = threadIdx.x;
    const int w = tid & 63;
    const int chi = tid >> 6;   // 0..3
    if (w < W_) {
        const float* xb = x + (long)b * CIN * HWP + h * W_ + w;
#pragma unroll
        for (int it = 0; it < 8; ++it) {
            const int c4 = it * 4 + chi;     // 0..31
            int pk = 0;
#pragma unroll
            for (int u = 0; u < 4; ++u) {
                float v = xb[(long)(c4 * 4 + u) * HWP];
                float q = fminf(127.f, fmaxf(-127.f, rintf(v * sx)));
                pk |= ((int)q & 0xff) << (u * 8);
            }
            ldsq[w * 33 + c4] = pk;
        }
    }
    __syncthreads();
    int4* dst = (int4*)(xq + (((long)b * HP + h + 1) * WP + 1) * CIN);
    for (int idx = tid; idx < W_ * 8; idx += 256) {
        const int ww = idx >> 3, c16 = idx & 7;
        int4 v;
        v.x = ldsq[ww * 33 + c16 * 4 + 0];
        v.y = ldsq[ww * 33 + c16 * 4 + 1];
        v.z = ldsq[ww * 33 + c16 * 4 + 2];
        v.w = ldsq[ww * 33 + c16 * 4 + 3];
        dst[ww * 8 + c16] = v;
    }
}

// ---------------- quantize w: OIHW f32 -> packed [chunk][cout][64] int8 ----------------
__global__ __launch_bounds__(256) void quant_w_kernel(const float* __restrict__ wt,
        const unsigned* __restrict__ scales, signed char* __restrict__ wq) {
    const int id = blockIdx.x * 256 + threadIdx.x;   // 73728 total
    if (id >= COUT * 9 * 32) return;
    const float sw = 127.0f / __uint_as_float(scales[1]);
    const int co = id / 288;
    const int r  = id % 288;
    const int t  = r / 32;    // tap
    const int c4 = r % 32;    // ci/4
    int pk = 0;
#pragma unroll
    for (int u = 0; u < 4; ++u) {
        float v = wt[(co * CIN + c4 * 4 + u) * 9 + t];
        float q = fminf(127.f, fmaxf(-127.f, rintf(v * sw)));
        pk |= ((int)q & 0xff) << (u * 8);
    }
    const int k = t * CIN + c4 * 4;
    const int chunk = k >> 6;
    const int off = k & 63;
    *(int*)(wq + (long)chunk * CHUNK_BYTES + co * 64 + off) = pk;
}

// ---------------- conv: LDS-pipelined MFMA implicit GEMM ----------------
// block 512 thr = 8 waves; tile 256 co x 128 px; wave tile 64x64.
// LDS K-major: As[buf][g][co][16B] (16KB), Bs[buf][g][px][16B] (8KB).
__global__ __launch_bounds__(512, 4) void conv_kernel(
        const signed char* __restrict__ xq, const signed char* __restrict__ wq,
        const float* __restrict__ bias, const unsigned* __restrict__ scales,
        float* __restrict__ out) {
    __shared__ signed char As[2][16384];
    __shared__ signed char Bs[2][8192];

    const int tid = threadIdx.x;
    const int lane = tid & 63;
    const int wv = tid >> 6;        // 0..7
    const int ln = lane & 15;
    const int g  = lane >> 4;

    const int wco = wv >> 1;        // co quarter 0..3
    const int wpx = wv & 1;         // px half 0..1
    const int px_blk = blockIdx.x * 128;

    // A staging: wave does insts e=wv*2, wv*2+1; e -> (gA=e>>2, qA=e&3)
    const int e0 = wv * 2, e1 = e0 + 1;
    const int gA0 = e0 >> 2, qA0 = e0 & 3;
    const int gA1 = e1 >> 2, qA1 = e1 & 3;
    const signed char* srcA0 = wq + (qA0 * 64 + lane) * 64 + gA0 * 16;
    const signed char* srcA1 = wq + (qA1 * 64 + lane) * 64 + gA1 * 16;
    const int ldsA0 = gA0 * 4096 + qA0 * 1024 + lane * 16;
    const int ldsA1 = gA1 * 4096 + qA1 * 1024 + lane * 16;

    // B staging: wave does inst wv -> (gB=wv>>1, halfB=wv&1); per-lane fixed px row
    const int gB = wv >> 1, halfB = wv & 1;
    const int pxs = px_blk + halfB * 64 + lane;
    const int bS = pxs / HWP, hwS = pxs % HWP;
    const int hS = hwS / W_, wS = hwS % W_;
    const signed char* srcB = xq + ((bS * HP + hS) * WP + wS) * CIN + gB * 16;
    const int ldsB = gB * 2048 + halfB * 1024 + lane * 16;

#define STAGE(c, buf) { \
    const int tap_ = (c) >> 1; \
    const int toff_ = ((tap_ / 3) * WP + (tap_ % 3)) * CIN + ((c) & 1) * 64; \
    gld_lds16(srcA0 + (c) * CHUNK_BYTES, &As[buf][ldsA0]); \
    gld_lds16(srcA1 + (c) * CHUNK_BYTES, &As[buf][ldsA1]); \
    gld_lds16(srcB + toff_, &Bs[buf][ldsB]); }

    int4v acc[4][4] = {};
    STAGE(0, 0);
#pragma unroll
    for (int c = 0; c < NCHUNK; ++c) {
        const int cur = c & 1;
        __syncthreads();                       // chunk c staged (vmcnt drained at barrier)
        if (c + 1 < NCHUNK) STAGE(c + 1, cur ^ 1);
        int4v Af[4], Bf[4];
#pragma unroll
        for (int i = 0; i < 4; ++i)
            Af[i] = *(const int4v*)&As[cur][g * 4096 + (wco * 64 + i * 16 + ln) * 16];
#pragma unroll
        for (int j = 0; j < 4; ++j)
            Bf[j] = *(const int4v*)&Bs[cur][g * 2048 + (wpx * 64 + j * 16 + ln) * 16];
#pragma unroll
        for (int i = 0; i < 4; ++i)
#pragma unroll
            for (int j = 0; j < 4; ++j)
                acc[i][j] = __builtin_amdgcn_mfma_i32_16x16x64_i8(Af[i], Bf[j], acc[i][j], 0, 0, 0);
    }
#undef STAGE

    const float ax = __uint_as_float(scales[0]);
    const float aw = __uint_as_float(scales[1]);
    const float inv = 1.0f / ((127.0f / ax) * (127.0f / aw));

    // D 16x16: col(=px) = lane&15, row(=co) = g*4 + r
#pragma unroll
    for (int i = 0; i < 4; ++i) {
        const int co = wco * 64 + i * 16 + g * 4;
#pragma unroll
        for (int r = 0; r < 4; ++r) {
            const float bsv = bias[co + r];
#pragma unroll
            for (int j = 0; j < 4; ++j) {
                const int px = px_blk + wpx * 64 + j * 16 + ln;
                const int b = px / HWP, hw = px % HWP;
                out[((long)(b * COUT + co + r)) * HWP + hw] = (float)acc[i][j][r] * inv + bsv;
            }
        }
    }
}

extern "C" void kernel_launch(void* const* d_in, const int* in_sizes, int n_in,
                              void* d_out, int out_size, void* d_ws, size_t ws_size,
                              hipStream_t stream) {
    const float* x  = (const float*)d_in[0];
    const float* wt = (const float*)d_in[1];
    const float* bs = (const float*)d_in[2];
    float* out = (float*)d_out;

    unsigned* scales = (unsigned*)d_ws;                  // [0]=amax_x, [1]=amax_w (bits)
    const size_t XQ_OFF   = 256;
    const size_t XQ_BYTES = (size_t)B_ * HP * WP * CIN;  // 13,778,944
    signed char* xq = (signed char*)d_ws + XQ_OFF;
    signed char* wq = xq + XQ_BYTES;

    pad_zero_kernel<<<B_, 256, 0, stream>>>(xq, scales);

    const long n4x = (long)B_ * CIN * H_ * W_ / 4;
    const long n4w = (long)COUT * CIN * 9 / 4;
    amax_kernel<<<2176, 256, 0, stream>>>((const float4*)x, n4x, (const float4*)wt, n4w, scales);

    quant_x_kernel<<<B_ * H_, 256, 0, stream>>>(x, scales, xq);
    quant_w_kernel<<<(COUT * 9 * 32 + 255) / 256, 256, 0, stream>>>(wt, scales, wq);

    conv_kernel<<<NPIX / 128, 512, 0, stream>>>(xq, wq, bs, scales, out);
}